// Round 2
// baseline (5237.567 us; speedup 1.0000x reference)
//
#include <hip/hip_runtime.h>
#include <math.h>

#define DD   4096   // feature dim
#define HH   2048   // hidden dim
#define NE   64     // experts
#define NTOK_BM 128 // K1 token tile
#define BN   128    // K1 hidden tile
#define BK   32
#define NT   (HH / BN)   // 16 hidden tiles

// ---------------------------------------------------------------------------
// K1: partial predictor logits.
// C[128x128] = x_tile @ W1_tile (full K=4096, fp32 acc), then
// relu(c + b1) * W2 reduced in FP64 over the 128-hidden tile
// -> one double per (token, hidden-tile) in pl[N][16]. Deterministic.
// ---------------------------------------------------------------------------
__global__ __launch_bounds__(256) void pred_gemm(
    const float* __restrict__ x, const float* __restrict__ W1,
    const float* __restrict__ b1, const float* __restrict__ W2,
    double* __restrict__ pl)
{
    __shared__ float As[BK][NTOK_BM];      // k-major: As[k][m]
    __shared__ float Bs[BK][BN];           // Bs[k][n]
    __shared__ double red[NTOK_BM][NT + 1]; // fp64 partials, +1 pad

    const int ht = blockIdx.x;     // hidden tile 0..15
    const int tm = blockIdx.y;     // token tile 0..127
    const int t  = threadIdx.x;
    const int tx = t & 15, ty = t >> 4;
    const int h0 = ht * BN;
    const int m0 = tm * NTOK_BM;

    float acc[8][8];
#pragma unroll
    for (int i = 0; i < 8; ++i)
#pragma unroll
        for (int j = 0; j < 8; ++j) acc[i][j] = 0.f;

    const int arow = t >> 1;          // 2 threads/row, 16 floats each
    const int acol = (t & 1) << 4;
    const int brow = t >> 3;          // 8 threads/row, 16 floats each
    const int bcol = (t & 7) << 4;
    const float* xrow = x  + (size_t)(m0 + arow) * DD + acol;
    const float* wrow = W1 + (size_t)brow * HH + h0 + bcol;

    for (int k0 = 0; k0 < DD; k0 += BK) {
        float4 a4[4], b4[4];
        const float4* ap = (const float4*)(xrow + k0);
#pragma unroll
        for (int i = 0; i < 4; ++i) a4[i] = ap[i];
        const float4* bp = (const float4*)(wrow + (size_t)k0 * HH);
#pragma unroll
        for (int i = 0; i < 4; ++i) b4[i] = bp[i];

        __syncthreads();
#pragma unroll
        for (int i = 0; i < 4; ++i) {   // A transpose into LDS
            As[acol + i * 4 + 0][arow] = a4[i].x;
            As[acol + i * 4 + 1][arow] = a4[i].y;
            As[acol + i * 4 + 2][arow] = a4[i].z;
            As[acol + i * 4 + 3][arow] = a4[i].w;
        }
#pragma unroll
        for (int i = 0; i < 4; ++i)
            *(float4*)&Bs[brow][bcol + i * 4] = b4[i];
        __syncthreads();

#pragma unroll 8
        for (int kk = 0; kk < BK; ++kk) {
            float4 a0  = *(const float4*)&As[kk][ty * 8];
            float4 a1  = *(const float4*)&As[kk][ty * 8 + 4];
            float4 bb0 = *(const float4*)&Bs[kk][tx * 8];
            float4 bb1 = *(const float4*)&Bs[kk][tx * 8 + 4];
            float av[8] = {a0.x, a0.y, a0.z, a0.w, a1.x, a1.y, a1.z, a1.w};
            float bv[8] = {bb0.x, bb0.y, bb0.z, bb0.w, bb1.x, bb1.y, bb1.z, bb1.w};
#pragma unroll
            for (int i = 0; i < 8; ++i)
#pragma unroll
                for (int j = 0; j < 8; ++j)
                    acc[i][j] = fmaf(av[i], bv[j], acc[i][j]);
        }
    }

    // fused epilogue: relu(c + b1) * W2, FP64 reduction over 128 hidden units
    __syncthreads();
#pragma unroll
    for (int r = 0; r < 8; ++r) {
        double s = 0.0;
#pragma unroll
        for (int c = 0; c < 8; ++c) {
            int h = h0 + tx * 8 + c;
            float v = acc[r][c] + b1[h];
            v = v > 0.f ? v : 0.f;
            s += (double)v * (double)W2[h];
        }
        red[ty * 8 + r][tx] = s;
    }
    __syncthreads();
    if (t < NTOK_BM) {
        double s = 0.0;
#pragma unroll
        for (int j = 0; j < NT; ++j) s += red[t][j];
        pl[(size_t)(m0 + t) * NT + ht] = s;
    }
}

// ---------------------------------------------------------------------------
// K2 (fused): gating logits in FP64 + full routing epilogue.
// Each block: 64 tokens x 64 experts, K=4096, fp64 accumulation (exact
// ordering vs the fp64 numpy reference). Then per-wave (1 wave = 1 token at
// a time, lane = expert): softmax, top-3 (lower-index tie-break), dynamic k
// from the predictor partials, renormalized weights, all 4 outputs.
// ---------------------------------------------------------------------------
__global__ __launch_bounds__(256) void gate_fused(
    const float* __restrict__ x, const float* __restrict__ W,
    const double* __restrict__ pl, const float* __restrict__ b2,
    float* __restrict__ out, int Ntok)
{
    // 33.3 KB shared, aliased: [As 8KB | Bs 8KB] during GEMM, D[64][65] after
    __shared__ __align__(16) char smem[64 * 65 * sizeof(double)];
    float (*As)[64] = (float(*)[64])smem;               // As[32][64] k-major
    float (*Bs)[64] = (float(*)[64])(smem + 8192);      // Bs[32][64]
    double (*Dm)[65] = (double(*)[65])smem;             // logits, after GEMM

    const int tm = blockIdx.x;
    const int t  = threadIdx.x;
    const int tx = t & 15, ty = t >> 4;
    const int m0 = tm * 64;

    double acc[4][4];
#pragma unroll
    for (int i = 0; i < 4; ++i)
#pragma unroll
        for (int j = 0; j < 4; ++j) acc[i][j] = 0.0;

    const int arow = t >> 2;            // 0..63, 4 threads/row, 8 floats each
    const int acol = (t & 3) << 3;
    const int brow = t >> 2;            // t<128: 0..31, 4 threads/row, 16 floats
    const int bcol = (t & 3) << 4;
    const float* xrow = x + (size_t)(m0 + arow) * DD + acol;
    const float* wrow = W + (size_t)brow * NE + bcol;

    for (int k0 = 0; k0 < DD; k0 += BK) {
        float4 a4[2], b4[4];
        const float4* ap = (const float4*)(xrow + k0);
        a4[0] = ap[0]; a4[1] = ap[1];
        if (t < 128) {
            const float4* bp = (const float4*)(wrow + (size_t)k0 * NE);
#pragma unroll
            for (int i = 0; i < 4; ++i) b4[i] = bp[i];
        }
        __syncthreads();
#pragma unroll
        for (int i = 0; i < 2; ++i) {
            As[acol + i * 4 + 0][arow] = a4[i].x;
            As[acol + i * 4 + 1][arow] = a4[i].y;
            As[acol + i * 4 + 2][arow] = a4[i].z;
            As[acol + i * 4 + 3][arow] = a4[i].w;
        }
        if (t < 128) {
#pragma unroll
            for (int i = 0; i < 4; ++i)
                *(float4*)&Bs[brow][bcol + i * 4] = b4[i];
        }
        __syncthreads();

#pragma unroll 8
        for (int kk = 0; kk < BK; ++kk) {
            float4 a = *(const float4*)&As[kk][ty * 4];
            float4 b = *(const float4*)&Bs[kk][tx * 4];
            double av[4] = {(double)a.x, (double)a.y, (double)a.z, (double)a.w};
            double bv[4] = {(double)b.x, (double)b.y, (double)b.z, (double)b.w};
#pragma unroll
            for (int i = 0; i < 4; ++i)
#pragma unroll
                for (int j = 0; j < 4; ++j)
                    acc[i][j] = fma(av[i], bv[j], acc[i][j]);
        }
    }

    // stash exact logits in LDS (aliases As/Bs — sync both sides)
    __syncthreads();
#pragma unroll
    for (int r = 0; r < 4; ++r)
#pragma unroll
        for (int c = 0; c < 4; ++c)
            Dm[ty * 4 + r][tx * 4 + c] = acc[r][c];
    __syncthreads();

    // ---- per-token epilogue: 4 waves x 16 tokens, lane = expert ----
    const int wave = t >> 6;
    const int lane = t & 63;
    const double b2v = (double)b2[0];

    for (int i = 0; i < 16; ++i) {
        const int tl = wave * 16 + i;
        const int token = m0 + tl;
        double g = Dm[tl][lane];

        // softmax over 64 experts (fp64)
        double mx = g;
#pragma unroll
        for (int o = 32; o > 0; o >>= 1) mx = fmax(mx, __shfl_xor(mx, o, 64));
        double e = exp(g - mx);
        double s = e;
#pragma unroll
        for (int o = 32; o > 0; o >>= 1) s += __shfl_xor(s, o, 64);
        double p = e / s;

        // top-3, ties -> lower index (jax.lax.top_k stable semantics)
        double pv = p; int pi = lane;
        double vt[3]; int it[3];
#pragma unroll
        for (int j = 0; j < 3; ++j) {
            double v = pv; int idx = pi;
#pragma unroll
            for (int o = 32; o > 0; o >>= 1) {
                double ov = __shfl_xor(v, o, 64);
                int    oi = __shfl_xor(idx, o, 64);
                if (ov > v || (ov == v && oi < idx)) { v = ov; idx = oi; }
            }
            vt[j] = v; it[j] = idx;
            if (lane == idx) pv = -1.0;   // probs >= 0, -1 never re-wins
        }

        // predictor logit: sum 16 fp64 partials, sigmoid, dynamic k
        double plv = (lane < NT) ? pl[(size_t)token * NT + lane] : 0.0;
#pragma unroll
        for (int o = 32; o > 0; o >>= 1) plv += __shfl_xor(plv, o, 64);
        double logit = plv + b2v;
        double score = 1.0 / (1.0 + exp(-logit));
        int k = (int)rint(score * 3.0) + 1;   // rint = round-half-even = jnp.round
        k = k < 1 ? 1 : (k > 3 ? 3 : k);

        // mask + renormalize
        double wmask[3]; double wsum = 0.0;
#pragma unroll
        for (int j = 0; j < 3; ++j) { wmask[j] = (j < k) ? vt[j] : 0.0; wsum += wmask[j]; }
        double denom = wsum + 1e-8;
        float wn[3];
#pragma unroll
        for (int j = 0; j < 3; ++j) wn[j] = (float)(wmask[j] / denom);

        // routing mask: 1.0 where expert in top-k and weight > 0
        float mval = 0.f;
#pragma unroll
        for (int j = 0; j < 3; ++j)
            if (it[j] == lane && wn[j] > 0.f) mval = 1.f;

        out[(size_t)6 * Ntok + (size_t)token * NE + lane] = mval;
        if (lane < 3) {
            out[(size_t)token * 3 + lane] = wn[lane];                        // weights
            out[(size_t)3 * Ntok + (size_t)token * 3 + lane] = (float)it[lane]; // indices
        }
        if (lane == 0) out[(size_t)70 * Ntok + token] = (float)k;            // dynamic k
    }
}

// ---------------------------------------------------------------------------
extern "C" void kernel_launch(void* const* d_in, const int* in_sizes, int n_in,
                              void* d_out, int out_size, void* d_ws, size_t ws_size,
                              hipStream_t stream)
{
    const float* x  = (const float*)d_in[0];
    const float* W  = (const float*)d_in[1];
    const float* W1 = (const float*)d_in[2];
    const float* b1 = (const float*)d_in[3];
    const float* W2 = (const float*)d_in[4];
    const float* b2 = (const float*)d_in[5];
    float* out = (float*)d_out;

    const int Ntok = in_sizes[0] / DD;           // 16384
    double* pl = (double*)d_ws;                  // Ntok * NT doubles = 2 MB

    pred_gemm<<<dim3(NT, Ntok / NTOK_BM), 256, 0, stream>>>(x, W1, b1, W2, pl);
    gate_fused<<<Ntok / 64, 256, 0, stream>>>(x, W, pl, b2, out, Ntok);
}

// Round 3
// 1890.335 us; speedup vs baseline: 2.7707x; 2.7707x over previous
//
#include <hip/hip_runtime.h>
#include <hip/hip_bf16.h>
#include <math.h>

#define DD   4096   // feature dim
#define HH   2048   // hidden dim
#define NE   64     // experts
#define BK   32
#define NT   16     // hidden tiles (HH/128)

typedef __attribute__((ext_vector_type(8))) short bf16x8;
typedef __attribute__((ext_vector_type(4))) float f32x4;

// async global->LDS, 16B per lane, dest = uniform base + lane*16
__device__ __forceinline__ void async16(void* lds, const void* g) {
    __builtin_amdgcn_global_load_lds(
        (const __attribute__((address_space(1))) unsigned int*)g,
        (__attribute__((address_space(3))) unsigned int*)lds, 16, 0, 0);
}

// split two floats into bf16 hi (RNE) + bf16 lo (RNE of exact residual)
__device__ __forceinline__ void split2(float a, float b, unsigned& hi, unsigned& lo) {
    __hip_bfloat162 h = __float22bfloat162_rn(make_float2(a, b));
    float2 hf = __bfloat1622float2(h);
    __hip_bfloat162 l = __float22bfloat162_rn(make_float2(a - hf.x, b - hf.y));
    __builtin_memcpy(&hi, &h, 4);
    __builtin_memcpy(&lo, &l, 4);
}

// ---------------------------------------------------------------------------
// presplit x -> hi/lo bf16 planes (row-major, same layout as x)
// ---------------------------------------------------------------------------
__global__ __launch_bounds__(256) void split_x(
    const float4* __restrict__ x, uint4* __restrict__ xh, uint4* __restrict__ xl,
    long n8)
{
    long i = (long)blockIdx.x * 256 + threadIdx.x;
    if (i >= n8) return;
    float4 a = x[2 * i], b = x[2 * i + 1];
    unsigned h0, l0, h1, l1, h2, l2, h3, l3;
    split2(a.x, a.y, h0, l0); split2(a.z, a.w, h1, l1);
    split2(b.x, b.y, h2, l2); split2(b.z, b.w, h3, l3);
    xh[i] = make_uint4(h0, h1, h2, h3);
    xl[i] = make_uint4(l0, l1, l2, l3);
}

// ---------------------------------------------------------------------------
// presplit + transpose W1[K][N] -> W1t hi/lo planes [N][K]
// ---------------------------------------------------------------------------
__global__ __launch_bounds__(256) void split_w1t(
    const float* __restrict__ W1,
    unsigned short* __restrict__ th, unsigned short* __restrict__ tl)
{
    __shared__ float ts[32][33];
    const int n0 = blockIdx.x * 32, k0 = blockIdx.y * 32;
    const int t = threadIdx.x;
    {
        int r = t >> 3, c4 = (t & 7) * 4;
        float4 v = *(const float4*)&W1[(size_t)(k0 + r) * HH + n0 + c4];
        ts[r][c4] = v.x; ts[r][c4 + 1] = v.y; ts[r][c4 + 2] = v.z; ts[r][c4 + 3] = v.w;
    }
    __syncthreads();
    int n = t >> 3, kk = (t & 7) * 4;
    float f0 = ts[kk][n], f1 = ts[kk + 1][n], f2 = ts[kk + 2][n], f3 = ts[kk + 3][n];
    unsigned h0, l0, h1, l1;
    split2(f0, f1, h0, l0); split2(f2, f3, h1, l1);
    *(uint2*)&th[(size_t)(n0 + n) * DD + k0 + kk] = make_uint2(h0, h1);
    *(uint2*)&tl[(size_t)(n0 + n) * DD + k0 + kk] = make_uint2(l0, l1);
}

// ---------------------------------------------------------------------------
// K1: predictor GEMM via bf16 MFMA, 3-product hi/lo split, fp32 MFMA acc.
// 128x128 tile, BK=32. LDS in fragment order: region[fb 0..7][lane][16B],
// so global_load_lds staging is contiguous and ds_read_b128 conflict-free.
// Wave w: m-half = w&1, n-half = w>>1, 4x4 frags of 16x16x32.
// Epilogue: relu(c+b1)*W2 reduced in fp64 -> pl[token][ntile].
// ---------------------------------------------------------------------------
template<bool PRE_A>
__global__ __launch_bounds__(256, 3) void pred_mfma(
    const float* __restrict__ x,
    const unsigned short* __restrict__ xh, const unsigned short* __restrict__ xl,
    const unsigned short* __restrict__ w1th, const unsigned short* __restrict__ w1tl,
    const float* __restrict__ b1, const float* __restrict__ W2,
    double* __restrict__ pl, int mtiles)
{
    __shared__ __align__(16) char lds[32768];
    char* Ah = lds;
    char* Al = lds + 8192;
    char* Bh = lds + 16384;
    char* Bl = lds + 24576;

    const int t = threadIdx.x, wv = t >> 6, ln = t & 63;
    // XCD swizzle: each XCD owns 2 n-tiles -> W1t slice (4MB) stays L2-resident
    const int lin = blockIdx.x;
    const int sub = lin >> 3;
    const int ntile = (lin & 7) * 2 + (sub & 1);
    const int mtile = sub >> 1;
    const int m0 = mtile * 128, n0 = ntile * 128;
    const int frow = ln & 15;            // fragment row/col within 16
    const int fkb  = (ln >> 4) * 8;      // fragment k offset (8 bf16)

    f32x4 acc[4][4];
#pragma unroll
    for (int i = 0; i < 4; ++i)
#pragma unroll
        for (int j = 0; j < 4; ++j) acc[i][j] = (f32x4){0.f, 0.f, 0.f, 0.f};

    // wave-role staging source (PRE_A path)
    const unsigned short* rsrc = nullptr; char* rdst = nullptr; size_t rbase = 0;
    if (PRE_A) {
        if (wv == 0)      { rsrc = xh;   rbase = (size_t)(m0 + frow) * DD; rdst = Ah; }
        else if (wv == 1) { rsrc = xl;   rbase = (size_t)(m0 + frow) * DD; rdst = Al; }
        else if (wv == 2) { rsrc = w1th; rbase = (size_t)(n0 + frow) * DD; rdst = Bh; }
        else              { rsrc = w1tl; rbase = (size_t)(n0 + frow) * DD; rdst = Bl; }
    }
    const unsigned short* gBh = w1th + (size_t)(n0 + frow) * DD + fkb;
    const unsigned short* gBl = w1tl + (size_t)(n0 + frow) * DD + fkb;

    const int mb = (wv & 1) * 4, nb = (wv >> 1) * 4;

    for (int kc = 0; kc < DD; kc += BK) {
        if (PRE_A) {
            const unsigned short* g = rsrc + rbase + kc + fkb;
#pragma unroll
            for (int fb = 0; fb < 8; ++fb)
                async16(rdst + fb * 1024, g + (size_t)fb * 16 * DD);
        } else {
            // B planes via async copy (4 issues/wave)
#pragma unroll
            for (int q = 0; q < 2; ++q) {
                int fb = wv * 2 + q;
                async16(Bh + fb * 1024, gBh + (size_t)fb * 16 * DD + kc);
                async16(Bl + fb * 1024, gBl + (size_t)fb * 16 * DD + kc);
            }
            // A: split fp32 x in-kernel, write fragment-order LDS (2 slots/thread)
#pragma unroll
            for (int s2 = 0; s2 < 2; ++s2) {
                int s = t + s2 * 256;
                int fb = s >> 6, sl = s & 63;
                int row = fb * 16 + (sl & 15), kb = (sl >> 4) * 8;
                const float* g = x + (size_t)(m0 + row) * DD + kc + kb;
                float4 a = *(const float4*)g, b = *(const float4*)(g + 4);
                unsigned h0, l0, h1, l1, h2, l2, h3, l3;
                split2(a.x, a.y, h0, l0); split2(a.z, a.w, h1, l1);
                split2(b.x, b.y, h2, l2); split2(b.z, b.w, h3, l3);
                *(uint4*)(Ah + s * 16) = make_uint4(h0, h1, h2, h3);
                *(uint4*)(Al + s * 16) = make_uint4(l0, l1, l2, l3);
            }
        }
        __syncthreads();   // drains vmcnt (async copies) + lgkm (ds writes)

        bf16x8 afh[4], afl[4], bfh[4], bfl[4];
#pragma unroll
        for (int i = 0; i < 4; ++i) {
            afh[i] = *(const bf16x8*)(Ah + (mb + i) * 1024 + ln * 16);
            afl[i] = *(const bf16x8*)(Al + (mb + i) * 1024 + ln * 16);
        }
#pragma unroll
        for (int j = 0; j < 4; ++j) {
            bfh[j] = *(const bf16x8*)(Bh + (nb + j) * 1024 + ln * 16);
            bfl[j] = *(const bf16x8*)(Bl + (nb + j) * 1024 + ln * 16);
        }
#pragma unroll
        for (int i = 0; i < 4; ++i)
#pragma unroll
            for (int j = 0; j < 4; ++j) {
                acc[i][j] = __builtin_amdgcn_mfma_f32_16x16x32_bf16(afh[i], bfh[j], acc[i][j], 0, 0, 0);
                acc[i][j] = __builtin_amdgcn_mfma_f32_16x16x32_bf16(afh[i], bfl[j], acc[i][j], 0, 0, 0);
                acc[i][j] = __builtin_amdgcn_mfma_f32_16x16x32_bf16(afl[i], bfh[j], acc[i][j], 0, 0, 0);
            }
        __syncthreads();
    }

    // epilogue: relu(c + b1) * W2, fp64 reduction. C layout: col=ln&15,
    // row=(ln>>4)*4+r per 16x16 frag.
    double* redd = (double*)lds;   // [2][128], aliases stage region (post-barrier)
    const int mh = wv & 1, nh = wv >> 1;
    float b1v[4], w2v[4];
#pragma unroll
    for (int j = 0; j < 4; ++j) {
        int col = n0 + nh * 64 + j * 16 + frow;
        b1v[j] = b1[col];
        w2v[j] = W2[col];
    }
#pragma unroll
    for (int i = 0; i < 4; ++i)
#pragma unroll
        for (int r = 0; r < 4; ++r) {
            double s = 0.0;
#pragma unroll
            for (int j = 0; j < 4; ++j) {
                float h = acc[i][j][r] + b1v[j];
                h = fmaxf(h, 0.f);
                s += (double)h * (double)w2v[j];
            }
#pragma unroll
            for (int o = 1; o < 16; o <<= 1) s += __shfl_xor(s, o, 64);
            if (frow == 0)
                redd[nh * 128 + mh * 64 + i * 16 + (ln >> 4) * 4 + r] = s;
        }
    __syncthreads();
    if (t < 128)
        pl[(size_t)(m0 + t) * NT + ntile] = redd[t] + redd[128 + t];
}

// ---------------------------------------------------------------------------
// Fallback K1 (round-2): fp32 VALU GEMM, used only if ws is too small.
// ---------------------------------------------------------------------------
__global__ __launch_bounds__(256) void pred_gemm(
    const float* __restrict__ x, const float* __restrict__ W1,
    const float* __restrict__ b1, const float* __restrict__ W2,
    double* __restrict__ pl)
{
    __shared__ float As[BK][128];
    __shared__ float Bs[BK][128];
    __shared__ double red[128][NT + 1];

    const int ht = blockIdx.x;
    const int tm = blockIdx.y;
    const int t  = threadIdx.x;
    const int tx = t & 15, ty = t >> 4;
    const int h0 = ht * 128;
    const int m0 = tm * 128;

    float acc[8][8];
#pragma unroll
    for (int i = 0; i < 8; ++i)
#pragma unroll
        for (int j = 0; j < 8; ++j) acc[i][j] = 0.f;

    const int arow = t >> 1, acol = (t & 1) << 4;
    const int brow = t >> 3, bcol = (t & 7) << 4;
    const float* xrow = x  + (size_t)(m0 + arow) * DD + acol;
    const float* wrow = W1 + (size_t)brow * HH + h0 + bcol;

    for (int k0 = 0; k0 < DD; k0 += BK) {
        float4 a4[4], b4[4];
        const float4* ap = (const float4*)(xrow + k0);
#pragma unroll
        for (int i = 0; i < 4; ++i) a4[i] = ap[i];
        const float4* bp = (const float4*)(wrow + (size_t)k0 * HH);
#pragma unroll
        for (int i = 0; i < 4; ++i) b4[i] = bp[i];
        __syncthreads();
#pragma unroll
        for (int i = 0; i < 4; ++i) {
            As[acol + i * 4 + 0][arow] = a4[i].x;
            As[acol + i * 4 + 1][arow] = a4[i].y;
            As[acol + i * 4 + 2][arow] = a4[i].z;
            As[acol + i * 4 + 3][arow] = a4[i].w;
        }
#pragma unroll
        for (int i = 0; i < 4; ++i)
            *(float4*)&Bs[brow][bcol + i * 4] = b4[i];
        __syncthreads();
#pragma unroll 8
        for (int kk = 0; kk < BK; ++kk) {
            float4 a0  = *(const float4*)&As[kk][ty * 8];
            float4 a1  = *(const float4*)&As[kk][ty * 8 + 4];
            float4 bb0 = *(const float4*)&Bs[kk][tx * 8];
            float4 bb1 = *(const float4*)&Bs[kk][tx * 8 + 4];
            float av[8] = {a0.x, a0.y, a0.z, a0.w, a1.x, a1.y, a1.z, a1.w};
            float bv[8] = {bb0.x, bb0.y, bb0.z, bb0.w, bb1.x, bb1.y, bb1.z, bb1.w};
#pragma unroll
            for (int i = 0; i < 8; ++i)
#pragma unroll
                for (int j = 0; j < 8; ++j)
                    acc[i][j] = fmaf(av[i], bv[j], acc[i][j]);
        }
    }
    __syncthreads();
#pragma unroll
    for (int r = 0; r < 8; ++r) {
        double s = 0.0;
#pragma unroll
        for (int c = 0; c < 8; ++c) {
            int h = h0 + tx * 8 + c;
            float v = acc[r][c] + b1[h];
            v = v > 0.f ? v : 0.f;
            s += (double)v * (double)W2[h];
        }
        red[ty * 8 + r][tx] = s;
    }
    __syncthreads();
    if (t < 128) {
        double s = 0.0;
#pragma unroll
        for (int j = 0; j < NT; ++j) s += red[t][j];
        pl[(size_t)(m0 + t) * NT + ht] = s;
    }
}

// ---------------------------------------------------------------------------
// K2 (fused): fp64 gating GEMM + routing epilogue (unchanged from round 2).
// ---------------------------------------------------------------------------
__global__ __launch_bounds__(256) void gate_fused(
    const float* __restrict__ x, const float* __restrict__ W,
    const double* __restrict__ pl, const float* __restrict__ b2,
    float* __restrict__ out, int Ntok)
{
    __shared__ __align__(16) char smem[64 * 65 * sizeof(double)];
    float (*As)[64] = (float(*)[64])smem;
    float (*Bs)[64] = (float(*)[64])(smem + 8192);
    double (*Dm)[65] = (double(*)[65])smem;

    const int tm = blockIdx.x;
    const int t  = threadIdx.x;
    const int tx = t & 15, ty = t >> 4;
    const int m0 = tm * 64;

    double acc[4][4];
#pragma unroll
    for (int i = 0; i < 4; ++i)
#pragma unroll
        for (int j = 0; j < 4; ++j) acc[i][j] = 0.0;

    const int arow = t >> 2, acol = (t & 3) << 3;
    const int brow = t >> 2, bcol = (t & 3) << 4;
    const float* xrow = x + (size_t)(m0 + arow) * DD + acol;
    const float* wrow = W + (size_t)brow * NE + bcol;

    for (int k0 = 0; k0 < DD; k0 += BK) {
        float4 a4[2], b4[4];
        const float4* ap = (const float4*)(xrow + k0);
        a4[0] = ap[0]; a4[1] = ap[1];
        if (t < 128) {
            const float4* bp = (const float4*)(wrow + (size_t)k0 * NE);
#pragma unroll
            for (int i = 0; i < 4; ++i) b4[i] = bp[i];
        }
        __syncthreads();
#pragma unroll
        for (int i = 0; i < 2; ++i) {
            As[acol + i * 4 + 0][arow] = a4[i].x;
            As[acol + i * 4 + 1][arow] = a4[i].y;
            As[acol + i * 4 + 2][arow] = a4[i].z;
            As[acol + i * 4 + 3][arow] = a4[i].w;
        }
        if (t < 128) {
#pragma unroll
            for (int i = 0; i < 4; ++i)
                *(float4*)&Bs[brow][bcol + i * 4] = b4[i];
        }
        __syncthreads();
#pragma unroll 8
        for (int kk = 0; kk < BK; ++kk) {
            float4 a = *(const float4*)&As[kk][ty * 4];
            float4 b = *(const float4*)&Bs[kk][tx * 4];
            double av[4] = {(double)a.x, (double)a.y, (double)a.z, (double)a.w};
            double bv[4] = {(double)b.x, (double)b.y, (double)b.z, (double)b.w};
#pragma unroll
            for (int i = 0; i < 4; ++i)
#pragma unroll
                for (int j = 0; j < 4; ++j)
                    acc[i][j] = fma(av[i], bv[j], acc[i][j]);
        }
    }

    __syncthreads();
#pragma unroll
    for (int r = 0; r < 4; ++r)
#pragma unroll
        for (int c = 0; c < 4; ++c)
            Dm[ty * 4 + r][tx * 4 + c] = acc[r][c];
    __syncthreads();

    const int wave = t >> 6;
    const int lane = t & 63;
    const double b2v = (double)b2[0];

    for (int i = 0; i < 16; ++i) {
        const int tl = wave * 16 + i;
        const int token = m0 + tl;
        double g = Dm[tl][lane];

        double mx = g;
#pragma unroll
        for (int o = 32; o > 0; o >>= 1) mx = fmax(mx, __shfl_xor(mx, o, 64));
        double e = exp(g - mx);
        double s = e;
#pragma unroll
        for (int o = 32; o > 0; o >>= 1) s += __shfl_xor(s, o, 64);
        double p = e / s;

        double pv = p; int pi = lane;
        double vt[3]; int it[3];
#pragma unroll
        for (int j = 0; j < 3; ++j) {
            double v = pv; int idx = pi;
#pragma unroll
            for (int o = 32; o > 0; o >>= 1) {
                double ov = __shfl_xor(v, o, 64);
                int    oi = __shfl_xor(idx, o, 64);
                if (ov > v || (ov == v && oi < idx)) { v = ov; idx = oi; }
            }
            vt[j] = v; it[j] = idx;
            if (lane == idx) pv = -1.0;
        }

        double plv = (lane < NT) ? pl[(size_t)token * NT + lane] : 0.0;
#pragma unroll
        for (int o = 32; o > 0; o >>= 1) plv += __shfl_xor(plv, o, 64);
        double logit = plv + b2v;
        double score = 1.0 / (1.0 + exp(-logit));
        int k = (int)rint(score * 3.0) + 1;
        k = k < 1 ? 1 : (k > 3 ? 3 : k);

        double wmask[3]; double wsum = 0.0;
#pragma unroll
        for (int j = 0; j < 3; ++j) { wmask[j] = (j < k) ? vt[j] : 0.0; wsum += wmask[j]; }
        double denom = wsum + 1e-8;
        float wn[3];
#pragma unroll
        for (int j = 0; j < 3; ++j) wn[j] = (float)(wmask[j] / denom);

        float mval = 0.f;
#pragma unroll
        for (int j = 0; j < 3; ++j)
            if (it[j] == lane && wn[j] > 0.f) mval = 1.f;

        out[(size_t)6 * Ntok + (size_t)token * NE + lane] = mval;
        if (lane < 3) {
            out[(size_t)token * 3 + lane] = wn[lane];
            out[(size_t)3 * Ntok + (size_t)token * 3 + lane] = (float)it[lane];
        }
        if (lane == 0) out[(size_t)70 * Ntok + token] = (float)k;
    }
}

// ---------------------------------------------------------------------------
extern "C" void kernel_launch(void* const* d_in, const int* in_sizes, int n_in,
                              void* d_out, int out_size, void* d_ws, size_t ws_size,
                              hipStream_t stream)
{
    const float* x  = (const float*)d_in[0];
    const float* W  = (const float*)d_in[1];
    const float* W1 = (const float*)d_in[2];
    const float* b1 = (const float*)d_in[3];
    const float* W2 = (const float*)d_in[4];
    const float* b2 = (const float*)d_in[5];
    float* out = (float*)d_out;

    const int Ntok = in_sizes[0] / DD;           // 16384

    // ws layout
    double* pl = (double*)d_ws;
    const size_t pl_b   = (size_t)Ntok * NT * sizeof(double);
    const size_t o_w1h  = (pl_b + 255) & ~(size_t)255;
    const size_t w1_b   = (size_t)DD * HH * 2;           // 16 MB per plane
    const size_t o_w1l  = o_w1h + w1_b;
    const size_t o_xh   = o_w1l + w1_b;
    const size_t x_b    = (size_t)Ntok * DD * 2;         // 128 MB per plane
    const size_t o_xl   = o_xh + x_b;
    const size_t need_w1   = o_xh;                       // ~34 MB
    const size_t need_full = o_xl + x_b;                 // ~290 MB

    const bool ok128 = (Ntok % 128) == 0;

    if (ok128 && ws_size >= need_w1) {
        unsigned short* w1th = (unsigned short*)((char*)d_ws + o_w1h);
        unsigned short* w1tl = (unsigned short*)((char*)d_ws + o_w1l);
        split_w1t<<<dim3(HH / 32, DD / 32), 256, 0, stream>>>(W1, w1th, w1tl);
        if (ws_size >= need_full) {
            unsigned short* xh = (unsigned short*)((char*)d_ws + o_xh);
            unsigned short* xl = (unsigned short*)((char*)d_ws + o_xl);
            long n8 = (long)Ntok * DD / 8;
            split_x<<<(int)((n8 + 255) / 256), 256, 0, stream>>>(
                (const float4*)x, (uint4*)xh, (uint4*)xl, n8);
            pred_mfma<true><<<16 * (Ntok / 128), 256, 0, stream>>>(
                x, xh, xl, w1th, w1tl, b1, W2, pl, Ntok / 128);
        } else {
            pred_mfma<false><<<16 * (Ntok / 128), 256, 0, stream>>>(
                x, nullptr, nullptr, w1th, w1tl, b1, W2, pl, Ntok / 128);
        }
    } else {
        pred_gemm<<<dim3(NT, Ntok / 128), 256, 0, stream>>>(x, W1, b1, W2, pl);
    }

    gate_fused<<<Ntok / 64, 256, 0, stream>>>(x, W, pl, b2, out, Ntok);
}

// Round 4
// 1753.535 us; speedup vs baseline: 2.9869x; 1.0780x over previous
//
#include <hip/hip_runtime.h>
#include <hip/hip_bf16.h>
#include <math.h>

#define DD   4096   // feature dim
#define HH   2048   // hidden dim
#define NE   64     // experts
#define BK   32
#define NT   16     // hidden tiles (HH/128)
#define GM   32     // gate token tile

typedef __attribute__((ext_vector_type(8))) short bf16x8;
typedef __attribute__((ext_vector_type(4))) float f32x4;

// async global->LDS, 16B per lane, dest = uniform base + lane*16
__device__ __forceinline__ void async16(void* lds, const void* g) {
    __builtin_amdgcn_global_load_lds(
        (const __attribute__((address_space(1))) unsigned int*)g,
        (__attribute__((address_space(3))) unsigned int*)lds, 16, 0, 0);
}

// split two floats into bf16 hi (RNE) + bf16 lo (RNE of exact residual)
__device__ __forceinline__ void split2(float a, float b, unsigned& hi, unsigned& lo) {
    __hip_bfloat162 h = __float22bfloat162_rn(make_float2(a, b));
    float2 hf = __bfloat1622float2(h);
    __hip_bfloat162 l = __float22bfloat162_rn(make_float2(a - hf.x, b - hf.y));
    __builtin_memcpy(&hi, &h, 4);
    __builtin_memcpy(&lo, &l, 4);
}

// ---------------------------------------------------------------------------
// presplit x -> hi/lo bf16 planes (row-major, same layout as x)
// ---------------------------------------------------------------------------
__global__ __launch_bounds__(256) void split_x(
    const float4* __restrict__ x, uint4* __restrict__ xh, uint4* __restrict__ xl,
    long n8)
{
    long i = (long)blockIdx.x * 256 + threadIdx.x;
    if (i >= n8) return;
    float4 a = x[2 * i], b = x[2 * i + 1];
    unsigned h0, l0, h1, l1, h2, l2, h3, l3;
    split2(a.x, a.y, h0, l0); split2(a.z, a.w, h1, l1);
    split2(b.x, b.y, h2, l2); split2(b.z, b.w, h3, l3);
    xh[i] = make_uint4(h0, h1, h2, h3);
    xl[i] = make_uint4(l0, l1, l2, l3);
}

// ---------------------------------------------------------------------------
// presplit + transpose W1[K][N] -> W1t hi/lo planes [N][K]
// ---------------------------------------------------------------------------
__global__ __launch_bounds__(256) void split_w1t(
    const float* __restrict__ W1,
    unsigned short* __restrict__ th, unsigned short* __restrict__ tl)
{
    __shared__ float ts[32][33];
    const int n0 = blockIdx.x * 32, k0 = blockIdx.y * 32;
    const int t = threadIdx.x;
    {
        int r = t >> 3, c4 = (t & 7) * 4;
        float4 v = *(const float4*)&W1[(size_t)(k0 + r) * HH + n0 + c4];
        ts[r][c4] = v.x; ts[r][c4 + 1] = v.y; ts[r][c4 + 2] = v.z; ts[r][c4 + 3] = v.w;
    }
    __syncthreads();
    int n = t >> 3, kk = (t & 7) * 4;
    float f0 = ts[kk][n], f1 = ts[kk + 1][n], f2 = ts[kk + 2][n], f3 = ts[kk + 3][n];
    unsigned h0, l0, h1, l1;
    split2(f0, f1, h0, l0); split2(f2, f3, h1, l1);
    *(uint2*)&th[(size_t)(n0 + n) * DD + k0 + kk] = make_uint2(h0, h1);
    *(uint2*)&tl[(size_t)(n0 + n) * DD + k0 + kk] = make_uint2(l0, l1);
}

// ---------------------------------------------------------------------------
// K1: predictor GEMM via bf16 MFMA, 3-product hi/lo split, fp32 MFMA acc.
// 128x128 tile, BK=32. LDS in fragment order: region[fb 0..7][lane][16B].
// PRE_A=true path uses same-buffer mid-barrier prefetch:
//   top barrier (drain asyncs k) -> ds_read all frags -> cheap barrier
//   -> issue asyncs k+1 into same buffer -> 48 MFMAs.
// Epilogue: relu(c+b1)*W2 reduced in fp64 -> pl[token][ntile].
// ---------------------------------------------------------------------------
template<bool PRE_A>
__global__ __launch_bounds__(256, 3) void pred_mfma(
    const float* __restrict__ x,
    const unsigned short* __restrict__ xh, const unsigned short* __restrict__ xl,
    const unsigned short* __restrict__ w1th, const unsigned short* __restrict__ w1tl,
    const float* __restrict__ b1, const float* __restrict__ W2,
    double* __restrict__ pl)
{
    __shared__ __align__(16) char lds[32768];
    char* Ah = lds;
    char* Al = lds + 8192;
    char* Bh = lds + 16384;
    char* Bl = lds + 24576;

    const int t = threadIdx.x, wv = t >> 6, ln = t & 63;
    // XCD swizzle: consecutive lins hit distinct XCDs; ntile fast within mtile
    const int lin = blockIdx.x;
    const int sub = lin >> 3;
    const int ntile = (lin & 7) * 2 + (sub & 1);
    const int mtile = sub >> 1;
    const int m0 = mtile * 128, n0 = ntile * 128;
    const int frow = ln & 15;            // fragment row/col within 16
    const int fkb  = (ln >> 4) * 8;      // fragment k offset (8 bf16)

    f32x4 acc[4][4];
#pragma unroll
    for (int i = 0; i < 4; ++i)
#pragma unroll
        for (int j = 0; j < 4; ++j) acc[i][j] = (f32x4){0.f, 0.f, 0.f, 0.f};

    // wave-role staging source (PRE_A path)
    const unsigned short* rsrc = nullptr; char* rdst = nullptr; size_t rbase = 0;
    if (PRE_A) {
        if (wv == 0)      { rsrc = xh;   rbase = (size_t)(m0 + frow) * DD; rdst = Ah; }
        else if (wv == 1) { rsrc = xl;   rbase = (size_t)(m0 + frow) * DD; rdst = Al; }
        else if (wv == 2) { rsrc = w1th; rbase = (size_t)(n0 + frow) * DD; rdst = Bh; }
        else              { rsrc = w1tl; rbase = (size_t)(n0 + frow) * DD; rdst = Bl; }
    }
    const unsigned short* gBh = w1th + (size_t)(n0 + frow) * DD + fkb;
    const unsigned short* gBl = w1tl + (size_t)(n0 + frow) * DD + fkb;

    const int mb = (wv & 1) * 4, nb = (wv >> 1) * 4;

    if (PRE_A) {
        // prologue: stage chunk 0
        {
            const unsigned short* g = rsrc + rbase + fkb;
#pragma unroll
            for (int fb = 0; fb < 8; ++fb)
                async16(rdst + fb * 1024, g + (size_t)fb * 16 * DD);
        }
        for (int kc = 0; kc < DD; kc += BK) {
            __syncthreads();   // drains asyncs for chunk kc

            bf16x8 afh[4], afl[4], bfh[4], bfl[4];
#pragma unroll
            for (int i = 0; i < 4; ++i) {
                afh[i] = *(const bf16x8*)(Ah + (mb + i) * 1024 + ln * 16);
                afl[i] = *(const bf16x8*)(Al + (mb + i) * 1024 + ln * 16);
                bfh[i] = *(const bf16x8*)(Bh + (nb + i) * 1024 + ln * 16);
                bfl[i] = *(const bf16x8*)(Bl + (nb + i) * 1024 + ln * 16);
            }
            __syncthreads();   // all waves' frag reads are in registers (lgkm-only)

            if (kc + BK < DD) {   // prefetch next chunk into the SAME buffer
                const unsigned short* g = rsrc + rbase + (kc + BK) + fkb;
#pragma unroll
                for (int fb = 0; fb < 8; ++fb)
                    async16(rdst + fb * 1024, g + (size_t)fb * 16 * DD);
            }

#pragma unroll
            for (int i = 0; i < 4; ++i)
#pragma unroll
                for (int j = 0; j < 4; ++j) {
                    acc[i][j] = __builtin_amdgcn_mfma_f32_16x16x32_bf16(afh[i], bfh[j], acc[i][j], 0, 0, 0);
                    acc[i][j] = __builtin_amdgcn_mfma_f32_16x16x32_bf16(afh[i], bfl[j], acc[i][j], 0, 0, 0);
                    acc[i][j] = __builtin_amdgcn_mfma_f32_16x16x32_bf16(afl[i], bfh[j], acc[i][j], 0, 0, 0);
                }
        }
    } else {
        // fallback: in-kernel split of fp32 x (round-3 structure, unchanged)
        for (int kc = 0; kc < DD; kc += BK) {
#pragma unroll
            for (int q = 0; q < 2; ++q) {
                int fb = wv * 2 + q;
                async16(Bh + fb * 1024, gBh + (size_t)fb * 16 * DD + kc);
                async16(Bl + fb * 1024, gBl + (size_t)fb * 16 * DD + kc);
            }
#pragma unroll
            for (int s2 = 0; s2 < 2; ++s2) {
                int s = t + s2 * 256;
                int fb = s >> 6, sl = s & 63;
                int row = fb * 16 + (sl & 15), kb = (sl >> 4) * 8;
                const float* g = x + (size_t)(m0 + row) * DD + kc + kb;
                float4 a = *(const float4*)g, b = *(const float4*)(g + 4);
                unsigned h0, l0, h1, l1, h2, l2, h3, l3;
                split2(a.x, a.y, h0, l0); split2(a.z, a.w, h1, l1);
                split2(b.x, b.y, h2, l2); split2(b.z, b.w, h3, l3);
                *(uint4*)(Ah + s * 16) = make_uint4(h0, h1, h2, h3);
                *(uint4*)(Al + s * 16) = make_uint4(l0, l1, l2, l3);
            }
            __syncthreads();

            bf16x8 afh[4], afl[4], bfh[4], bfl[4];
#pragma unroll
            for (int i = 0; i < 4; ++i) {
                afh[i] = *(const bf16x8*)(Ah + (mb + i) * 1024 + ln * 16);
                afl[i] = *(const bf16x8*)(Al + (mb + i) * 1024 + ln * 16);
                bfh[i] = *(const bf16x8*)(Bh + (nb + i) * 1024 + ln * 16);
                bfl[i] = *(const bf16x8*)(Bl + (nb + i) * 1024 + ln * 16);
            }
#pragma unroll
            for (int i = 0; i < 4; ++i)
#pragma unroll
                for (int j = 0; j < 4; ++j) {
                    acc[i][j] = __builtin_amdgcn_mfma_f32_16x16x32_bf16(afh[i], bfh[j], acc[i][j], 0, 0, 0);
                    acc[i][j] = __builtin_amdgcn_mfma_f32_16x16x32_bf16(afh[i], bfl[j], acc[i][j], 0, 0, 0);
                    acc[i][j] = __builtin_amdgcn_mfma_f32_16x16x32_bf16(afl[i], bfh[j], acc[i][j], 0, 0, 0);
                }
            __syncthreads();
        }
    }

    // epilogue: relu(c + b1) * W2, fp64 reduction. C layout: col=ln&15,
    // row=(ln>>4)*4+r per 16x16 frag.
    __syncthreads();
    double* redd = (double*)lds;   // [2][128]
    const int mh = wv & 1, nh = wv >> 1;
    float b1v[4], w2v[4];
#pragma unroll
    for (int j = 0; j < 4; ++j) {
        int col = n0 + nh * 64 + j * 16 + frow;
        b1v[j] = b1[col];
        w2v[j] = W2[col];
    }
#pragma unroll
    for (int i = 0; i < 4; ++i)
#pragma unroll
        for (int r = 0; r < 4; ++r) {
            double s = 0.0;
#pragma unroll
            for (int j = 0; j < 4; ++j) {
                float h = acc[i][j][r] + b1v[j];
                h = fmaxf(h, 0.f);
                s += (double)h * (double)w2v[j];
            }
#pragma unroll
            for (int o = 1; o < 16; o <<= 1) s += __shfl_xor(s, o, 64);
            if (frow == 0)
                redd[nh * 128 + mh * 64 + i * 16 + (ln >> 4) * 4 + r] = s;
        }
    __syncthreads();
    if (t < 128)
        pl[(size_t)(m0 + t) * NT + ntile] = redd[t] + redd[128 + t];
}

// ---------------------------------------------------------------------------
// Fallback K1 (round-2): fp32 VALU GEMM, used only if ws is too small.
// ---------------------------------------------------------------------------
__global__ __launch_bounds__(256) void pred_gemm(
    const float* __restrict__ x, const float* __restrict__ W1,
    const float* __restrict__ b1, const float* __restrict__ W2,
    double* __restrict__ pl)
{
    __shared__ float As[BK][128];
    __shared__ float Bs[BK][128];
    __shared__ double red[128][NT + 1];

    const int ht = blockIdx.x;
    const int tm = blockIdx.y;
    const int t  = threadIdx.x;
    const int tx = t & 15, ty = t >> 4;
    const int h0 = ht * 128;
    const int m0 = tm * 128;

    float acc[8][8];
#pragma unroll
    for (int i = 0; i < 8; ++i)
#pragma unroll
        for (int j = 0; j < 8; ++j) acc[i][j] = 0.f;

    const int arow = t >> 1, acol = (t & 1) << 4;
    const int brow = t >> 3, bcol = (t & 7) << 4;
    const float* xrow = x  + (size_t)(m0 + arow) * DD + acol;
    const float* wrow = W1 + (size_t)brow * HH + h0 + bcol;

    for (int k0 = 0; k0 < DD; k0 += BK) {
        float4 a4[4], b4[4];
        const float4* ap = (const float4*)(xrow + k0);
#pragma unroll
        for (int i = 0; i < 4; ++i) a4[i] = ap[i];
        const float4* bp = (const float4*)(wrow + (size_t)k0 * HH);
#pragma unroll
        for (int i = 0; i < 4; ++i) b4[i] = bp[i];
        __syncthreads();
#pragma unroll
        for (int i = 0; i < 4; ++i) {
            As[acol + i * 4 + 0][arow] = a4[i].x;
            As[acol + i * 4 + 1][arow] = a4[i].y;
            As[acol + i * 4 + 2][arow] = a4[i].z;
            As[acol + i * 4 + 3][arow] = a4[i].w;
        }
#pragma unroll
        for (int i = 0; i < 4; ++i)
            *(float4*)&Bs[brow][bcol + i * 4] = b4[i];
        __syncthreads();
#pragma unroll 8
        for (int kk = 0; kk < BK; ++kk) {
            float4 a0  = *(const float4*)&As[kk][ty * 8];
            float4 a1  = *(const float4*)&As[kk][ty * 8 + 4];
            float4 bb0 = *(const float4*)&Bs[kk][tx * 8];
            float4 bb1 = *(const float4*)&Bs[kk][tx * 8 + 4];
            float av[8] = {a0.x, a0.y, a0.z, a0.w, a1.x, a1.y, a1.z, a1.w};
            float bv[8] = {bb0.x, bb0.y, bb0.z, bb0.w, bb1.x, bb1.y, bb1.z, bb1.w};
#pragma unroll
            for (int i = 0; i < 8; ++i)
#pragma unroll
                for (int j = 0; j < 8; ++j)
                    acc[i][j] = fmaf(av[i], bv[j], acc[i][j]);
        }
    }
    __syncthreads();
#pragma unroll
    for (int r = 0; r < 8; ++r) {
        double s = 0.0;
#pragma unroll
        for (int c = 0; c < 8; ++c) {
            int h = h0 + tx * 8 + c;
            float v = acc[r][c] + b1[h];
            v = v > 0.f ? v : 0.f;
            s += (double)v * (double)W2[h];
        }
        red[ty * 8 + r][tx] = s;
    }
    __syncthreads();
    if (t < 128) {
        double s = 0.0;
#pragma unroll
        for (int j = 0; j < NT; ++j) s += red[t][j];
        pl[(size_t)(m0 + t) * NT + ht] = s;
    }
}

// ---------------------------------------------------------------------------
// K2 (fused): fp64 gating GEMM + routing epilogue.
// Round-4: 32-token tiles (grid 512 -> 2 blocks/CU) + register prefetch of
// the next K-chunk so global latency hides behind the dfma phase. Per-element
// fp64 accumulation order (k ascending) identical to round 3.
// ---------------------------------------------------------------------------
__global__ __launch_bounds__(256) void gate_fused(
    const float* __restrict__ x, const float* __restrict__ W,
    const double* __restrict__ pl, const float* __restrict__ b2,
    float* __restrict__ out, int Ntok)
{
    __shared__ __align__(16) char smem[GM * (NE + 1) * sizeof(double)]; // 16.6 KB
    float (*As)[GM] = (float(*)[GM])smem;                  // [BK][GM]  4 KB
    float (*Bs)[NE] = (float(*)[NE])(smem + BK * GM * 4);  // [BK][NE]  8 KB
    double (*Dm)[NE + 1] = (double(*)[NE + 1])smem;        // logits after GEMM

    const int tm = blockIdx.x;
    const int t  = threadIdx.x;
    const int tx = t & 15, ty = t >> 4;    // output: rows ty*2..+1, cols tx*4..+3
    const int m0 = tm * GM;

    double acc[2][4];
#pragma unroll
    for (int i = 0; i < 2; ++i)
#pragma unroll
        for (int j = 0; j < 4; ++j) acc[i][j] = 0.0;

    const int arow = t >> 3, acol = (t & 7) * 4;   // A: 32 rows x 32 k, 1 float4/thr
    const int brow = t >> 3, bcol = (t & 7) * 8;   // B: 32 k x 64,     2 float4/thr
    const float* xrow = x + (size_t)(m0 + arow) * DD + acol;
    const float* wrow = W + (size_t)brow * NE + bcol;

    // prologue: chunk-0 registers
    float4 a4  = *(const float4*)xrow;
    float4 b40 = *(const float4*)wrow;
    float4 b41 = *(const float4*)(wrow + 4);

    for (int k0 = 0; k0 < DD; k0 += BK) {
        __syncthreads();                 // previous compute done reading LDS
        As[acol + 0][arow] = a4.x;       // A transpose to k-major
        As[acol + 1][arow] = a4.y;
        As[acol + 2][arow] = a4.z;
        As[acol + 3][arow] = a4.w;
        *(float4*)&Bs[brow][bcol]     = b40;
        *(float4*)&Bs[brow][bcol + 4] = b41;
        __syncthreads();

        if (k0 + BK < DD) {              // prefetch next chunk into registers
            a4  = *(const float4*)(xrow + k0 + BK);
            b40 = *(const float4*)(wrow + (size_t)(k0 + BK) * NE);
            b41 = *(const float4*)(wrow + (size_t)(k0 + BK) * NE + 4);
        }

#pragma unroll 8
        for (int kk = 0; kk < BK; ++kk) {
            double a0 = (double)As[kk][ty * 2];
            double a1 = (double)As[kk][ty * 2 + 1];
            float4 b = *(const float4*)&Bs[kk][tx * 4];
            double bv[4] = {(double)b.x, (double)b.y, (double)b.z, (double)b.w};
#pragma unroll
            for (int j = 0; j < 4; ++j) {
                acc[0][j] = fma(a0, bv[j], acc[0][j]);
                acc[1][j] = fma(a1, bv[j], acc[1][j]);
            }
        }
    }

    __syncthreads();
#pragma unroll
    for (int r = 0; r < 2; ++r)
#pragma unroll
        for (int c = 0; c < 4; ++c)
            Dm[ty * 2 + r][tx * 4 + c] = acc[r][c];
    __syncthreads();

    // ---- per-token epilogue: 4 waves x 8 tokens, lane = expert ----
    const int wave = t >> 6;
    const int lane = t & 63;
    const double b2v = (double)b2[0];

    for (int i = 0; i < 8; ++i) {
        const int tl = wave * 8 + i;
        const int token = m0 + tl;
        double g = Dm[tl][lane];

        double mx = g;
#pragma unroll
        for (int o = 32; o > 0; o >>= 1) mx = fmax(mx, __shfl_xor(mx, o, 64));
        double e = exp(g - mx);
        double s = e;
#pragma unroll
        for (int o = 32; o > 0; o >>= 1) s += __shfl_xor(s, o, 64);
        double p = e / s;

        double pv = p; int pi = lane;
        double vt[3]; int it[3];
#pragma unroll
        for (int j = 0; j < 3; ++j) {
            double v = pv; int idx = pi;
#pragma unroll
            for (int o = 32; o > 0; o >>= 1) {
                double ov = __shfl_xor(v, o, 64);
                int    oi = __shfl_xor(idx, o, 64);
                if (ov > v || (ov == v && oi < idx)) { v = ov; idx = oi; }
            }
            vt[j] = v; it[j] = idx;
            if (lane == idx) pv = -1.0;
        }

        double plv = (lane < NT) ? pl[(size_t)token * NT + lane] : 0.0;
#pragma unroll
        for (int o = 32; o > 0; o >>= 1) plv += __shfl_xor(plv, o, 64);
        double logit = plv + b2v;
        double score = 1.0 / (1.0 + exp(-logit));
        int k = (int)rint(score * 3.0) + 1;
        k = k < 1 ? 1 : (k > 3 ? 3 : k);

        double wmask[3]; double wsum = 0.0;
#pragma unroll
        for (int j = 0; j < 3; ++j) { wmask[j] = (j < k) ? vt[j] : 0.0; wsum += wmask[j]; }
        double denom = wsum + 1e-8;
        float wn[3];
#pragma unroll
        for (int j = 0; j < 3; ++j) wn[j] = (float)(wmask[j] / denom);

        float mval = 0.f;
#pragma unroll
        for (int j = 0; j < 3; ++j)
            if (it[j] == lane && wn[j] > 0.f) mval = 1.f;

        out[(size_t)6 * Ntok + (size_t)token * NE + lane] = mval;
        if (lane < 3) {
            out[(size_t)token * 3 + lane] = wn[lane];
            out[(size_t)3 * Ntok + (size_t)token * 3 + lane] = (float)it[lane];
        }
        if (lane == 0) out[(size_t)70 * Ntok + token] = (float)k;
    }
}

// ---------------------------------------------------------------------------
extern "C" void kernel_launch(void* const* d_in, const int* in_sizes, int n_in,
                              void* d_out, int out_size, void* d_ws, size_t ws_size,
                              hipStream_t stream)
{
    const float* x  = (const float*)d_in[0];
    const float* W  = (const float*)d_in[1];
    const float* W1 = (const float*)d_in[2];
    const float* b1 = (const float*)d_in[3];
    const float* W2 = (const float*)d_in[4];
    const float* b2 = (const float*)d_in[5];
    float* out = (float*)d_out;

    const int Ntok = in_sizes[0] / DD;           // 16384

    // ws layout
    double* pl = (double*)d_ws;
    const size_t pl_b   = (size_t)Ntok * NT * sizeof(double);
    const size_t o_w1h  = (pl_b + 255) & ~(size_t)255;
    const size_t w1_b   = (size_t)DD * HH * 2;           // 16 MB per plane
    const size_t o_w1l  = o_w1h + w1_b;
    const size_t o_xh   = o_w1l + w1_b;
    const size_t x_b    = (size_t)Ntok * DD * 2;         // 128 MB per plane
    const size_t o_xl   = o_xh + x_b;
    const size_t need_w1   = o_xh;                       // ~34 MB
    const size_t need_full = o_xl + x_b;                 // ~290 MB

    const bool ok128 = (Ntok % 128) == 0;

    if (ok128 && ws_size >= need_w1) {
        unsigned short* w1th = (unsigned short*)((char*)d_ws + o_w1h);
        unsigned short* w1tl = (unsigned short*)((char*)d_ws + o_w1l);
        split_w1t<<<dim3(HH / 32, DD / 32), 256, 0, stream>>>(W1, w1th, w1tl);
        if (ws_size >= need_full) {
            unsigned short* xh = (unsigned short*)((char*)d_ws + o_xh);
            unsigned short* xl = (unsigned short*)((char*)d_ws + o_xl);
            long n8 = (long)Ntok * DD / 8;
            split_x<<<(int)((n8 + 255) / 256), 256, 0, stream>>>(
                (const float4*)x, (uint4*)xh, (uint4*)xl, n8);
            pred_mfma<true><<<16 * (Ntok / 128), 256, 0, stream>>>(
                x, xh, xl, w1th, w1tl, b1, W2, pl);
        } else {
            pred_mfma<false><<<16 * (Ntok / 128), 256, 0, stream>>>(
                x, nullptr, nullptr, w1th, w1tl, b1, W2, pl);
        }
    } else {
        pred_gemm<<<dim3(NT, Ntok / 128), 256, 0, stream>>>(x, W1, b1, W2, pl);
    }

    gate_fused<<<Ntok / GM, 256, 0, stream>>>(x, W, pl, b2, out, Ntok);
}